// Round 1
// baseline (369.350 us; speedup 1.0000x reference)
//
#include <hip/hip_runtime.h>
#include <math.h>

// Problem constants
#define BG   64      // graphs
#define NN   2048    // nodes per graph
#define DD   256     // hidden dim
#define GG   4       // groups
#define CQ   16      // 12 class queries + 4 group queries fused

// Workspace layout (in floats)
//  q16     : [16][256]            at 0         (rows 0-11 class queries, 12-15 group queries)
//  h       : [4][512]             at 4096      (projector hidden)
//  scores  : [64][16][2048]       at 6144      (raw scores, then normalized softmax p in-place)
//  partial : [64][4][16][256]     at 2103296   (per-node-chunk pooled partials)
static constexpr size_t WS_Q16 = 0;
static constexpr size_t WS_H   = 4096;
static constexpr size_t WS_S   = 6144;
static constexpr size_t WS_P   = 6144 + (size_t)BG * CQ * NN;   // 2103296

// ---------------------------------------------------------------------------
// A1: h[g][j] = relu(q[g] . w1[g][:,j] + b1[g][j]); also copy group queries
// into Q16 rows 12..15.  grid 64 = 4 groups x 16 j-chunks of 32, block 256.
__global__ __launch_bounds__(256) void kA1(const float* __restrict__ gq,
                                           const float* __restrict__ w1,
                                           const float* __restrict__ b1,
                                           float* __restrict__ ws) {
    int blk = blockIdx.x;
    int g   = blk >> 4;
    int jb  = (blk & 15) * 32;
    int t   = threadIdx.x;
    __shared__ float qlds[256];
    qlds[t] = gq[g * 256 + t];
    if ((blk & 15) == 0) ws[WS_Q16 + (12 + g) * 256 + t] = gq[g * 256 + t];
    __syncthreads();
    int jl = t & 31, dp = t >> 5;              // 32 j x 8 d-parts
    float acc = 0.f;
    const float* wp = w1 + ((size_t)g * 256) * 512 + jb + jl;
    #pragma unroll 8
    for (int i = 0; i < 32; ++i) {
        int d = dp * 32 + i;
        acc += qlds[d] * wp[(size_t)d * 512];
    }
    __shared__ float red[8][33];
    red[dp][jl] = acc;
    __syncthreads();
    if (dp == 0) {
        float s = 0.f;
        #pragma unroll
        for (int p = 0; p < 8; ++p) s += red[p][jl];
        s += b1[g * 512 + jb + jl];
        ws[WS_H + g * 512 + jb + jl] = fmaxf(s, 0.f);
    }
}

// A2: flat[g][k] = h[g] . w2[g][:,k] + b2[g][k] -> Q16 rows 0..11.
// grid 96 = 4 groups x 24 k-chunks of 32, block 256.
__global__ __launch_bounds__(256) void kA2(const float* __restrict__ w2,
                                           const float* __restrict__ b2,
                                           float* __restrict__ ws) {
    int blk = blockIdx.x;
    int g   = blk / 24;
    int kb  = (blk % 24) * 32;
    int t   = threadIdx.x;
    __shared__ float hlds[512];
    hlds[t]       = ws[WS_H + g * 512 + t];
    hlds[t + 256] = ws[WS_H + g * 512 + t + 256];
    __syncthreads();
    int kl = t & 31, dp = t >> 5;              // 32 k x 8 d-parts (64 each)
    float acc = 0.f;
    const float* wp = w2 + ((size_t)g * 512) * 768 + kb + kl;
    #pragma unroll 8
    for (int i = 0; i < 64; ++i) {
        int jj = dp * 64 + i;
        acc += hlds[jj] * wp[(size_t)jj * 768];
    }
    __shared__ float red[8][33];
    red[dp][kl] = acc;
    __syncthreads();
    if (dp == 0) {
        float s = 0.f;
        #pragma unroll
        for (int p = 0; p < 8; ++p) s += red[p][kl];
        ws[WS_Q16 + g * 768 + kb + kl] = s + b2[g * 768 + kb + kl];
    }
}

// ---------------------------------------------------------------------------
// B: scores[b][c][n] = (Q16[c] . x[n]) / 16.  2 nodes/thread, Q16 in LDS.
// grid 256 blocks x 512 nodes, block 256.
__global__ __launch_bounds__(256) void kB(const float* __restrict__ x,
                                          const float* __restrict__ q16,
                                          float* __restrict__ scores) {
    __shared__ float4 qlds[CQ * 64];           // [c][d-chunk]
    int t = threadIdx.x;
    const float4* qg = (const float4*)q16;
    for (int i = t; i < CQ * 64; i += 256) qlds[i] = qg[i];
    __syncthreads();

    int n0 = blockIdx.x * 512;
    const float4* xa = (const float4*)x + (size_t)(n0 + t) * 64;
    const float4* xb = (const float4*)x + (size_t)(n0 + t + 256) * 64;

    float acc1[CQ], acc2[CQ];
    #pragma unroll
    for (int c = 0; c < CQ; ++c) { acc1[c] = 0.f; acc2[c] = 0.f; }

    #pragma unroll 2
    for (int ch = 0; ch < 64; ++ch) {
        float4 a = xa[ch];
        float4 b = xb[ch];
        #pragma unroll
        for (int c = 0; c < CQ; ++c) {
            float4 q = qlds[c * 64 + ch];
            acc1[c] += q.x * a.x + q.y * a.y + q.z * a.z + q.w * a.w;
            acc2[c] += q.x * b.x + q.y * b.y + q.z * b.z + q.w * b.w;
        }
    }
    int bgi = n0 >> 11;                        // graph index (512 | 2048 so no straddle)
    int nl  = n0 & 2047;                       // node offset within graph
    float* srow = scores + (size_t)bgi * CQ * NN + nl;
    #pragma unroll
    for (int c = 0; c < CQ; ++c) {
        srow[(size_t)c * NN + t]       = acc1[c] * 0.0625f;
        srow[(size_t)c * NN + t + 256] = acc2[c] * 0.0625f;
    }
}

// ---------------------------------------------------------------------------
// C: softmax over n for each (b,c); write normalized p in-place; rows c<12
// also go to the attn12 output.  grid 1024 = b*16+c, block 256.
__global__ __launch_bounds__(256) void kC(float* __restrict__ scores,
                                          float* __restrict__ out_attn) {
    int bc = blockIdx.x;
    int b  = bc >> 4, c = bc & 15;
    int t  = threadIdx.x;
    int wave = t >> 6, lane = t & 63;
    float4* row = (float4*)(scores + (size_t)(b * CQ + c) * NN);
    float4 v1 = row[t];
    float4 v2 = row[t + 256];

    float m = fmaxf(fmaxf(fmaxf(v1.x, v1.y), fmaxf(v1.z, v1.w)),
                    fmaxf(fmaxf(v2.x, v2.y), fmaxf(v2.z, v2.w)));
    #pragma unroll
    for (int off = 32; off; off >>= 1) m = fmaxf(m, __shfl_xor(m, off, 64));
    __shared__ float wmax[4], wsum[4], bmax, bsum;
    if (lane == 0) wmax[wave] = m;
    __syncthreads();
    if (t == 0) bmax = fmaxf(fmaxf(wmax[0], wmax[1]), fmaxf(wmax[2], wmax[3]));
    __syncthreads();
    m = bmax;

    float4 e1, e2;
    e1.x = __expf(v1.x - m); e1.y = __expf(v1.y - m);
    e1.z = __expf(v1.z - m); e1.w = __expf(v1.w - m);
    e2.x = __expf(v2.x - m); e2.y = __expf(v2.y - m);
    e2.z = __expf(v2.z - m); e2.w = __expf(v2.w - m);
    float s = e1.x + e1.y + e1.z + e1.w + e2.x + e2.y + e2.z + e2.w;
    #pragma unroll
    for (int off = 32; off; off >>= 1) s += __shfl_xor(s, off, 64);
    if (lane == 0) wsum[wave] = s;
    __syncthreads();
    if (t == 0) bsum = wsum[0] + wsum[1] + wsum[2] + wsum[3];
    __syncthreads();
    float inv = 1.f / bsum;
    e1.x *= inv; e1.y *= inv; e1.z *= inv; e1.w *= inv;
    e2.x *= inv; e2.y *= inv; e2.z *= inv; e2.w *= inv;
    row[t]       = e1;
    row[t + 256] = e2;
    if (c < 12) {
        float4* ar = (float4*)out_attn + (size_t)(b * 12 + c) * (NN / 4);
        ar[t]       = e1;
        ar[t + 256] = e2;
    }
}

// ---------------------------------------------------------------------------
// D: partial pooled.  grid 256 = b*4 + part; block 256 (4 waves x 64 lanes).
// Wave handles 128 consecutive nodes; lane owns one float4 of D -> x loads
// are 1KB fully-coalesced per wave; p loads are wave-uniform.
__global__ __launch_bounds__(256) void kD(const float* __restrict__ x,
                                          const float* __restrict__ p,
                                          float* __restrict__ partial) {
    int blk = blockIdx.x;
    int b = blk >> 2, part = blk & 3;
    int t = threadIdx.x, wave = t >> 6, lane = t & 63;

    float4 acc[CQ];
    #pragma unroll
    for (int c = 0; c < CQ; ++c) acc[c] = make_float4(0.f, 0.f, 0.f, 0.f);

    const float4* xf = (const float4*)x;
    const float4* pf = (const float4*)p;
    int nbase = part * 512 + wave * 128;                       // graph-local
    size_t xrow = ((size_t)b * NN + nbase) * 64 + lane;
    size_t prow = (size_t)b * CQ * (NN / 4) + (nbase >> 2);

    for (int nn = 0; nn < 128; nn += 4) {
        float4 x0 = xf[xrow + (size_t)nn * 64];
        float4 x1 = xf[xrow + (size_t)(nn + 1) * 64];
        float4 x2 = xf[xrow + (size_t)(nn + 2) * 64];
        float4 x3 = xf[xrow + (size_t)(nn + 3) * 64];
        #pragma unroll
        for (int c = 0; c < CQ; ++c) {
            float4 pv = pf[prow + (size_t)c * (NN / 4) + (nn >> 2)];
            acc[c].x += pv.x * x0.x + pv.y * x1.x + pv.z * x2.x + pv.w * x3.x;
            acc[c].y += pv.x * x0.y + pv.y * x1.y + pv.z * x2.y + pv.w * x3.y;
            acc[c].z += pv.x * x0.z + pv.y * x1.z + pv.z * x2.z + pv.w * x3.z;
            acc[c].w += pv.x * x0.w + pv.y * x1.w + pv.z * x2.w + pv.w * x3.w;
        }
    }

    __shared__ float sdata[CQ * 256];
    for (int w = 0; w < 4; ++w) {
        if (wave == w) {
            #pragma unroll
            for (int c = 0; c < CQ; ++c) {
                float* dst = &sdata[c * 256 + lane * 4];
                if (w == 0) {
                    dst[0] = acc[c].x; dst[1] = acc[c].y;
                    dst[2] = acc[c].z; dst[3] = acc[c].w;
                } else {
                    dst[0] += acc[c].x; dst[1] += acc[c].y;
                    dst[2] += acc[c].z; dst[3] += acc[c].w;
                }
            }
        }
        __syncthreads();
    }
    float* po = partial + (size_t)blk * (CQ * 256);
    for (int i = t; i < CQ * 256; i += 256) po[i] = sdata[i];
}

// ---------------------------------------------------------------------------
// E: reduce 4 partials -> pooled row; LayerNorm; Linear(256,128)+ReLU;
// Linear(128,1) -> logits.  grid 1024 = b*16+c, block 256.
__global__ __launch_bounds__(256) void kE(const float* __restrict__ partial,
        const float* __restrict__ lnG12, const float* __restrict__ lnB12,
        const float* __restrict__ wA12,  const float* __restrict__ bA12,
        const float* __restrict__ wB12,  const float* __restrict__ bB12,
        const float* __restrict__ lnG4,  const float* __restrict__ lnB4,
        const float* __restrict__ wA4,   const float* __restrict__ bA4,
        const float* __restrict__ wB4,   const float* __restrict__ bB4,
        float* __restrict__ out) {
    int bc = blockIdx.x;
    int b = bc >> 4, c = bc & 15;
    int t = threadIdx.x;

    float v = 0.f;
    size_t base = (size_t)b * 4 * (CQ * 256) + (size_t)c * 256 + t;
    #pragma unroll
    for (int part = 0; part < 4; ++part) v += partial[base + (size_t)part * (CQ * 256)];

    __shared__ float red[256];
    __shared__ float smu, svar;
    red[t] = v;
    __syncthreads();
    for (int s = 128; s > 0; s >>= 1) { if (t < s) red[t] += red[t + s]; __syncthreads(); }
    if (t == 0) smu = red[0] * (1.f / 256.f);
    __syncthreads();
    float mu = smu;
    float dv = v - mu;
    red[t] = dv * dv;
    __syncthreads();
    for (int s = 128; s > 0; s >>= 1) { if (t < s) red[t] += red[t + s]; __syncthreads(); }
    if (t == 0) svar = red[0] * (1.f / 256.f);
    __syncthreads();

    bool is12 = (c < 12);
    const float* lg = is12 ? lnG12 : lnG4;
    const float* lb = is12 ? lnB12 : lnB4;
    const float* wA = is12 ? wA12  : wA4;
    const float* bA = is12 ? bA12  : bA4;
    const float* wB = is12 ? wB12  : wB4;
    const float* bB = is12 ? bB12  : bB4;

    __shared__ float ylds[256];
    __shared__ float hlds[128];
    float y = dv * rsqrtf(svar + 1e-5f) * lg[t] + lb[t];
    ylds[t] = y;
    __syncthreads();
    if (t < 128) {
        float hh = bA[t];
        for (int d = 0; d < 256; ++d) hh += ylds[d] * wA[d * 128 + t];
        hlds[t] = fmaxf(hh, 0.f);
    }
    __syncthreads();
    if (t < 64) {
        float pp = hlds[t] * wB[t] + hlds[t + 64] * wB[t + 64];
        #pragma unroll
        for (int off = 32; off; off >>= 1) pp += __shfl_xor(pp, off, 64);
        if (t == 0) {
            float logit = pp + bB[0];
            if (is12) out[b * 12 + c] = logit;
            else      out[768 + b * 4 + (c - 12)] = logit;
        }
    }
}

// ---------------------------------------------------------------------------
extern "C" void kernel_launch(void* const* d_in, const int* in_sizes, int n_in,
                              void* d_out, int out_size, void* d_ws, size_t ws_size,
                              hipStream_t stream) {
    const float* x     = (const float*)d_in[0];   // [131072, 256]
    // d_in[1] = batch (int64) — equal sorted segments, unused
    const float* gq    = (const float*)d_in[2];   // [4, 256]
    const float* w1    = (const float*)d_in[3];   // [4, 256, 512]
    const float* b1    = (const float*)d_in[4];   // [4, 512]
    const float* w2    = (const float*)d_in[5];   // [4, 512, 768]
    const float* b2    = (const float*)d_in[6];   // [4, 768]
    const float* ln12g = (const float*)d_in[7];
    const float* ln12b = (const float*)d_in[8];
    const float* w12a  = (const float*)d_in[9];   // [256, 128]
    const float* b12a  = (const float*)d_in[10];
    const float* w12b  = (const float*)d_in[11];  // [128, 1]
    const float* b12b  = (const float*)d_in[12];
    const float* ln4g  = (const float*)d_in[13];
    const float* ln4b  = (const float*)d_in[14];
    const float* w4a   = (const float*)d_in[15];
    const float* b4a   = (const float*)d_in[16];
    const float* w4b   = (const float*)d_in[17];
    const float* b4b   = (const float*)d_in[18];

    float* out     = (float*)d_out;               // [768 logits12][256 logits4][1572864 attn12]
    float* ws      = (float*)d_ws;
    float* q16     = ws + WS_Q16;
    float* scores  = ws + WS_S;
    float* partial = ws + WS_P;

    kA1<<<64,  256, 0, stream>>>(gq, w1, b1, ws);
    kA2<<<96,  256, 0, stream>>>(w2, b2, ws);
    kB <<<256, 256, 0, stream>>>(x, q16, scores);
    kC <<<1024,256, 0, stream>>>(scores, out + 1024);
    kD <<<256, 256, 0, stream>>>(x, scores, partial);
    kE <<<1024,256, 0, stream>>>(partial,
                                 ln12g, ln12b, w12a, b12a, w12b, b12b,
                                 ln4g,  ln4b,  w4a,  b4a,  w4b,  b4b,
                                 out);
}

// Round 2
// 315.339 us; speedup vs baseline: 1.1713x; 1.1713x over previous
//
#include <hip/hip_runtime.h>
#include <math.h>

// Problem constants
#define BG   64      // graphs
#define NN   2048    // nodes per graph
#define DD   256     // hidden dim
#define CQ   16      // 12 class queries + 4 group queries fused

// Workspace layout (in floats)
//  q16     : [16][256]            at 0
//  h       : [4][512]             at 4096
//  scores  : [64][16][2048]       at 6144      (raw scores, then softmax p in-place)
//  partial : [64][P][16][256]     at 2103296
static constexpr size_t WS_Q16 = 0;
static constexpr size_t WS_H   = 4096;
static constexpr size_t WS_S   = 6144;
static constexpr size_t WS_P   = 6144 + (size_t)BG * CQ * NN;   // 2103296

// ---------------------------------------------------------------------------
// A1: h[g][j] = relu(q[g] . w1[g][:,j] + b1[g][j]); copy group queries to
// Q16 rows 12..15.  grid 64 = 4 groups x 16 j-chunks of 32, block 256.
__global__ __launch_bounds__(256) void kA1(const float* __restrict__ gq,
                                           const float* __restrict__ w1,
                                           const float* __restrict__ b1,
                                           float* __restrict__ ws) {
    int blk = blockIdx.x;
    int g   = blk >> 4;
    int jb  = (blk & 15) * 32;
    int t   = threadIdx.x;
    __shared__ float qlds[256];
    qlds[t] = gq[g * 256 + t];
    if ((blk & 15) == 0) ws[WS_Q16 + (12 + g) * 256 + t] = gq[g * 256 + t];
    __syncthreads();
    int jl = t & 31, dp = t >> 5;              // 32 j x 8 d-parts
    float acc = 0.f;
    const float* wp = w1 + ((size_t)g * 256) * 512 + jb + jl;
    #pragma unroll 8
    for (int i = 0; i < 32; ++i) {
        int d = dp * 32 + i;
        acc += qlds[d] * wp[(size_t)d * 512];
    }
    __shared__ float red[8][33];
    red[dp][jl] = acc;
    __syncthreads();
    if (dp == 0) {
        float s = 0.f;
        #pragma unroll
        for (int p = 0; p < 8; ++p) s += red[p][jl];
        s += b1[g * 512 + jb + jl];
        ws[WS_H + g * 512 + jb + jl] = fmaxf(s, 0.f);
    }
}

// A2: flat[g][k] = h[g] . w2[g][:,k] + b2[g][k] -> Q16 rows 0..11.
// grid 192 = 4 groups x 48 k-chunks of 16, block 256 (16 k x 16 d-parts).
__global__ __launch_bounds__(256) void kA2(const float* __restrict__ w2,
                                           const float* __restrict__ b2,
                                           float* __restrict__ ws) {
    int blk = blockIdx.x;
    int g   = blk / 48;
    int kb  = (blk % 48) * 16;
    int t   = threadIdx.x;
    __shared__ float hlds[512];
    hlds[t]       = ws[WS_H + g * 512 + t];
    hlds[t + 256] = ws[WS_H + g * 512 + t + 256];
    __syncthreads();
    int kl = t & 15, dp = t >> 4;              // 16 k x 16 d-parts (32 each)
    float acc = 0.f;
    const float* wp = w2 + ((size_t)g * 512) * 768 + kb + kl;
    #pragma unroll 8
    for (int i = 0; i < 32; ++i) {
        int jj = dp * 32 + i;
        acc += hlds[jj] * wp[(size_t)jj * 768];
    }
    __shared__ float red[16][17];
    red[dp][kl] = acc;
    __syncthreads();
    if (dp == 0) {
        float s = 0.f;
        #pragma unroll
        for (int p = 0; p < 16; ++p) s += red[p][kl];
        ws[WS_Q16 + g * 768 + kb + kl] = s + b2[g * 768 + kb + kl];
    }
}

// ---------------------------------------------------------------------------
// B: scores[b][c][n] = (Q16[c] . x[n]) / 16.  1 node/thread, Q16 in LDS.
// grid 512 blocks x 256 nodes, block 256.
__global__ __launch_bounds__(256) void kB(const float* __restrict__ x,
                                          const float* __restrict__ q16,
                                          float* __restrict__ scores) {
    __shared__ float4 qlds[CQ * 64];           // [c][d-chunk]
    int t = threadIdx.x;
    const float4* qg = (const float4*)q16;
    for (int i = t; i < CQ * 64; i += 256) qlds[i] = qg[i];
    __syncthreads();

    int n0 = blockIdx.x * 256;
    const float4* xa = (const float4*)x + (size_t)(n0 + t) * 64;

    float acc[CQ];
    #pragma unroll
    for (int c = 0; c < CQ; ++c) acc[c] = 0.f;

    #pragma unroll 4
    for (int ch = 0; ch < 64; ++ch) {
        float4 a = xa[ch];
        #pragma unroll
        for (int c = 0; c < CQ; ++c) {
            float4 q = qlds[c * 64 + ch];
            acc[c] += q.x * a.x + q.y * a.y + q.z * a.z + q.w * a.w;
        }
    }
    int bgi = n0 >> 11;                        // 256 | 2048 so no straddle
    int nl  = n0 & 2047;
    float* srow = scores + (size_t)bgi * CQ * NN + nl;
    #pragma unroll
    for (int c = 0; c < CQ; ++c) srow[(size_t)c * NN + t] = acc[c] * 0.0625f;
}

// ---------------------------------------------------------------------------
// C: softmax over n per (b,c); normalized p in-place; rows c<12 also to
// attn12 output.  grid 1024 = b*16+c, block 256.
__global__ __launch_bounds__(256) void kC(float* __restrict__ scores,
                                          float* __restrict__ out_attn) {
    int bc = blockIdx.x;
    int b  = bc >> 4, c = bc & 15;
    int t  = threadIdx.x;
    int wave = t >> 6, lane = t & 63;
    float4* row = (float4*)(scores + (size_t)(b * CQ + c) * NN);
    float4 v1 = row[t];
    float4 v2 = row[t + 256];

    float m = fmaxf(fmaxf(fmaxf(v1.x, v1.y), fmaxf(v1.z, v1.w)),
                    fmaxf(fmaxf(v2.x, v2.y), fmaxf(v2.z, v2.w)));
    #pragma unroll
    for (int off = 32; off; off >>= 1) m = fmaxf(m, __shfl_xor(m, off, 64));
    __shared__ float wmax[4], wsum[4];
    if (lane == 0) wmax[wave] = m;
    __syncthreads();
    m = fmaxf(fmaxf(wmax[0], wmax[1]), fmaxf(wmax[2], wmax[3]));

    float4 e1, e2;
    e1.x = __expf(v1.x - m); e1.y = __expf(v1.y - m);
    e1.z = __expf(v1.z - m); e1.w = __expf(v1.w - m);
    e2.x = __expf(v2.x - m); e2.y = __expf(v2.y - m);
    e2.z = __expf(v2.z - m); e2.w = __expf(v2.w - m);
    float s = e1.x + e1.y + e1.z + e1.w + e2.x + e2.y + e2.z + e2.w;
    #pragma unroll
    for (int off = 32; off; off >>= 1) s += __shfl_xor(s, off, 64);
    if (lane == 0) wsum[wave] = s;
    __syncthreads();
    float inv = 1.f / (wsum[0] + wsum[1] + wsum[2] + wsum[3]);
    e1.x *= inv; e1.y *= inv; e1.z *= inv; e1.w *= inv;
    e2.x *= inv; e2.y *= inv; e2.z *= inv; e2.w *= inv;
    row[t]       = e1;
    row[t + 256] = e2;
    if (c < 12) {
        float4* ar = (float4*)out_attn + (size_t)(b * 12 + c) * (NN / 4);
        ar[t]       = e1;
        ar[t + 256] = e2;
    }
}

// ---------------------------------------------------------------------------
// D: partial pooled.  grid 64*P = (b,part); block 256 (4 waves x 64 lanes).
// Wave handles NN/P/4 consecutive nodes; lane owns one float4 of D.
template<int P>
__global__ __launch_bounds__(256) void kD(const float* __restrict__ x,
                                          const float* __restrict__ p,
                                          float* __restrict__ partial) {
    constexpr int NPB = NN / P;                 // nodes per block
    constexpr int NPW = NPB / 4;                // nodes per wave
    int blk = blockIdx.x;
    int b = blk / P, part = blk % P;
    int t = threadIdx.x, wave = t >> 6, lane = t & 63;

    float4 acc[CQ];
    #pragma unroll
    for (int c = 0; c < CQ; ++c) acc[c] = make_float4(0.f, 0.f, 0.f, 0.f);

    const float4* xf = (const float4*)x;
    const float4* pf = (const float4*)p;
    int nbase = part * NPB + wave * NPW;        // graph-local
    size_t xrow = ((size_t)b * NN + nbase) * 64 + lane;
    size_t prow = (size_t)b * CQ * (NN / 4) + (nbase >> 2);

    for (int nn = 0; nn < NPW; nn += 4) {
        float4 x0 = xf[xrow + (size_t)nn * 64];
        float4 x1 = xf[xrow + (size_t)(nn + 1) * 64];
        float4 x2 = xf[xrow + (size_t)(nn + 2) * 64];
        float4 x3 = xf[xrow + (size_t)(nn + 3) * 64];
        #pragma unroll
        for (int c = 0; c < CQ; ++c) {
            float4 pv = pf[prow + (size_t)c * (NN / 4) + (nn >> 2)];
            acc[c].x += pv.x * x0.x + pv.y * x1.x + pv.z * x2.x + pv.w * x3.x;
            acc[c].y += pv.x * x0.y + pv.y * x1.y + pv.z * x2.y + pv.w * x3.y;
            acc[c].z += pv.x * x0.z + pv.y * x1.z + pv.z * x2.z + pv.w * x3.z;
            acc[c].w += pv.x * x0.w + pv.y * x1.w + pv.z * x2.w + pv.w * x3.w;
        }
    }

    __shared__ float sdata[CQ * 256];
    for (int w = 0; w < 4; ++w) {
        if (wave == w) {
            #pragma unroll
            for (int c = 0; c < CQ; ++c) {
                float* dst = &sdata[c * 256 + lane * 4];
                if (w == 0) {
                    dst[0] = acc[c].x; dst[1] = acc[c].y;
                    dst[2] = acc[c].z; dst[3] = acc[c].w;
                } else {
                    dst[0] += acc[c].x; dst[1] += acc[c].y;
                    dst[2] += acc[c].z; dst[3] += acc[c].w;
                }
            }
        }
        __syncthreads();
    }
    float* po = partial + (size_t)blk * (CQ * 256);
    for (int i = t; i < CQ * 256; i += 256) po[i] = sdata[i];
}

// ---------------------------------------------------------------------------
// E: reduce P partials -> pooled row; LayerNorm; Linear(256,128)+ReLU;
// Linear(128,1) -> logits.  grid 1024 = b*16+c, block 256.
template<int P>
__global__ __launch_bounds__(256) void kE(const float* __restrict__ partial,
        const float* __restrict__ lnG12, const float* __restrict__ lnB12,
        const float* __restrict__ wA12,  const float* __restrict__ bA12,
        const float* __restrict__ wB12,  const float* __restrict__ bB12,
        const float* __restrict__ lnG4,  const float* __restrict__ lnB4,
        const float* __restrict__ wA4,   const float* __restrict__ bA4,
        const float* __restrict__ wB4,   const float* __restrict__ bB4,
        float* __restrict__ out) {
    int bc = blockIdx.x;
    int b = bc >> 4, c = bc & 15;
    int t = threadIdx.x, wave = t >> 6, lane = t & 63;

    float v = 0.f;
    size_t base = ((size_t)b * P * CQ + c) * 256 + t;
    #pragma unroll
    for (int part = 0; part < P; ++part) v += partial[base + (size_t)part * (CQ * 256)];

    // mean
    __shared__ float wr1[4], wr2[4];
    float s = v;
    #pragma unroll
    for (int off = 32; off; off >>= 1) s += __shfl_xor(s, off, 64);
    if (lane == 0) wr1[wave] = s;
    __syncthreads();
    float mu = (wr1[0] + wr1[1] + wr1[2] + wr1[3]) * (1.f / 256.f);
    float dv = v - mu;
    s = dv * dv;
    #pragma unroll
    for (int off = 32; off; off >>= 1) s += __shfl_xor(s, off, 64);
    if (lane == 0) wr2[wave] = s;
    __syncthreads();
    float var = (wr2[0] + wr2[1] + wr2[2] + wr2[3]) * (1.f / 256.f);

    bool is12 = (c < 12);
    const float* lg = is12 ? lnG12 : lnG4;
    const float* lb = is12 ? lnB12 : lnB4;
    const float* wA = is12 ? wA12  : wA4;
    const float* bA = is12 ? bA12  : bA4;
    const float* wB = is12 ? wB12  : wB4;
    const float* bB = is12 ? bB12  : bB4;

    __shared__ float ylds[256];
    __shared__ float hred[256];
    __shared__ float hlds[128];
    float y = dv * rsqrtf(var + 1e-5f) * lg[t] + lb[t];
    ylds[t] = y;
    __syncthreads();
    // hidden: 2 threads per output j, each sums 128 dims
    {
        int j = t & 127, half = t >> 7;
        float hh = 0.f;
        const float* wc = wA + (size_t)half * 128 * 128 + j;
        #pragma unroll 4
        for (int d = 0; d < 128; ++d) hh += ylds[half * 128 + d] * wc[(size_t)d * 128];
        hred[t] = hh;
    }
    __syncthreads();
    if (t < 128) hlds[t] = fmaxf(hred[t] + hred[t + 128] + bA[t], 0.f);
    __syncthreads();
    if (t < 64) {
        float pp = hlds[t] * wB[t] + hlds[t + 64] * wB[t + 64];
        #pragma unroll
        for (int off = 32; off; off >>= 1) pp += __shfl_xor(pp, off, 64);
        if (t == 0) {
            float logit = pp + bB[0];
            if (is12) out[b * 12 + c] = logit;
            else      out[768 + b * 4 + (c - 12)] = logit;
        }
    }
}

// ---------------------------------------------------------------------------
extern "C" void kernel_launch(void* const* d_in, const int* in_sizes, int n_in,
                              void* d_out, int out_size, void* d_ws, size_t ws_size,
                              hipStream_t stream) {
    const float* x     = (const float*)d_in[0];   // [131072, 256]
    const float* gq    = (const float*)d_in[2];   // [4, 256]
    const float* w1    = (const float*)d_in[3];   // [4, 256, 512]
    const float* b1    = (const float*)d_in[4];   // [4, 512]
    const float* w2    = (const float*)d_in[5];   // [4, 512, 768]
    const float* b2    = (const float*)d_in[6];   // [4, 768]
    const float* ln12g = (const float*)d_in[7];
    const float* ln12b = (const float*)d_in[8];
    const float* w12a  = (const float*)d_in[9];   // [256, 128]
    const float* b12a  = (const float*)d_in[10];
    const float* w12b  = (const float*)d_in[11];  // [128, 1]
    const float* b12b  = (const float*)d_in[12];
    const float* ln4g  = (const float*)d_in[13];
    const float* ln4b  = (const float*)d_in[14];
    const float* w4a   = (const float*)d_in[15];
    const float* b4a   = (const float*)d_in[16];
    const float* w4b   = (const float*)d_in[17];
    const float* b4b   = (const float*)d_in[18];

    float* out     = (float*)d_out;               // [768 logits12][256 logits4][1572864 attn12]
    float* ws      = (float*)d_ws;
    float* q16     = ws + WS_Q16;
    float* scores  = ws + WS_S;
    float* partial = ws + WS_P;

    kA1<<<64,  256, 0, stream>>>(gq, w1, b1, ws);
    kA2<<<192, 256, 0, stream>>>(w2, b2, ws);
    kB <<<512, 256, 0, stream>>>(x, q16, scores);
    kC <<<1024,256, 0, stream>>>(scores, out + 1024);

    // pick P by available workspace (same every call -> graph-safe)
    size_t need16 = (WS_P + (size_t)BG * 16 * CQ * 256) * sizeof(float);
    size_t need8  = (WS_P + (size_t)BG * 8  * CQ * 256) * sizeof(float);
    if (ws_size >= need16) {
        kD<16><<<BG * 16, 256, 0, stream>>>(x, scores, partial);
        kE<16><<<1024, 256, 0, stream>>>(partial,
                ln12g, ln12b, w12a, b12a, w12b, b12b,
                ln4g,  ln4b,  w4a,  b4a,  w4b,  b4b, out);
    } else if (ws_size >= need8) {
        kD<8><<<BG * 8, 256, 0, stream>>>(x, scores, partial);
        kE<8><<<1024, 256, 0, stream>>>(partial,
                ln12g, ln12b, w12a, b12a, w12b, b12b,
                ln4g,  ln4b,  w4a,  b4a,  w4b,  b4b, out);
    } else {
        kD<4><<<BG * 4, 256, 0, stream>>>(x, scores, partial);
        kE<4><<<1024, 256, 0, stream>>>(partial,
                ln12g, ln12b, w12a, b12a, w12b, b12b,
                ln4g,  ln4b,  w4a,  b4a,  w4b,  b4b, out);
    }
}